// Round 8
// baseline (314.856 us; speedup 1.0000x reference)
//
#include <hip/hip_runtime.h>
#include <math.h>

// TGV-2 PDHG, B=2, H=W=256, T=128.
// R21: ONE barrier per iteration (was 2). R20's discriminating probe proved
// the R9-family is phase-LATENCY-bound: -25% VALU ops on 66% of blocks was
// exactly neutral (252.9us), as were -18% work (R14) and fewer DS ops (R12).
// The only lever left is the number of serial phases/iter.
// The 2nd phase only exchanged fresh p,q at (r-1) and (c-1). Those are
// COMPUTABLE from data already published: each thread maintains shadow
// copies of the up-row dual state (p1U,p2U,q11U,q22U,q12U as v2f) and
// left-col dual state (5 scalars), updated every iteration with the
// identical formulas on identical inputs (ub/vb rows r-1,r from LDS; own
// registers are the down/right-neighbor terms). Issue is free (R20), so the
// ~55 extra ops/iter are hidden; the p/q publish + arrays + second barrier
// vanish. ub/vb double-buffered so iter t+1's publish doesn't race iter t's
// reads (barrier t+1 separates iter-t reads from iter-t+2 writes).
// Shadow init from global at base-256 / base-1 (prologue only; zeros at
// t0==0 matching p=q=0). Trapezoid validity aligns: thread r's last primal
// is at t=r-1, where row r-1 is still in the publish set.
// Valid-pixel math = same expressions, same order -> absmax must stay
// exactly 7.450581e-09 (built-in certificate).
// Config otherwise = R14: region 32x48, tile 16x32, halo 8 = iters/launch,
// 16 launches, 256 blocks (1/CU), 768 threads (12 waves), packed v2f math,
// rsq+min projection, row gating, init folded into launch 0, final launch
// stores only u. LDS now 2x(ub A + vb 2A) = 6A + pads = 37.9KB.

namespace {

typedef float v2f __attribute__((ext_vector_type(2)));

constexpr int kN = 2 * 256 * 256;
constexpr float kTau = 0.28867513459481287f;  // 1/sqrt(12) (f32)
constexpr float kSigma = kTau;
constexpr float kInv1pTau = 1.0f / (1.0f + kTau);

constexpr int RR = 32;          // region rows (H)
constexpr int RC = 48;          // region cols (W)
constexpr int A = RR * RC;      // 1536 floats per LDS array
constexpr int PAD = 128;        // rim-overread safety pads (front/back)
constexpr int TILE_R = 16;
constexpr int TILE_C = 32;
constexpr int HALO = 8;         // = iterations per launch
constexpr int NLAUNCH = 128 / HALO;      // 16
constexpr int NTHREADS = RR * (RC / 2);  // 768 = 12 waves

__device__ __forceinline__ float4 ld4(const float* p) {
  return *reinterpret_cast<const float4*>(p);
}

// ws layout: 10 arrays of kN floats: ub, v1, v2, vb1, vb2, p1, p2, q11, q22, q12
__global__ __launch_bounds__(NTHREADS, 3) void tgv8_kernel(
    const float* __restrict__ f, const float* __restrict__ rp,
    float* __restrict__ ug, float* __restrict__ ws, int t0) {
  float* ubg = ws + 0 * kN;
  float* v1g = ws + 1 * kN;
  float* v2g = ws + 2 * kN;
  float* vb1g = ws + 3 * kN;
  float* vb2g = ws + 4 * kN;
  float* p1g = ws + 5 * kN;
  float* p2g = ws + 6 * kN;
  float* q11g = ws + 7 * kN;
  float* q22g = ws + 8 * kN;
  float* q12g = ws + 9 * kN;

  // LDS: double-buffered ub (A each) + interleaved vb pair (2A each)
  __shared__ __align__(16) float smem[2 * PAD + 6 * A];
  float* ubB0 = smem + PAD;
  float* ubB1 = ubB0 + A;
  float* vbB0 = ubB1 + A;       // [vb1, vb2] interleaved per pixel
  float* vbB1 = vbB0 + 2 * A;

  const int tid = threadIdx.x;
  const int r = tid / 24;        // region row 0..31
  const int c = (tid % 24) * 2;  // region col (float2-aligned)
  const int rc = r * RC + c;

  const int gi = blockIdx.y * TILE_R + r - HALO;  // global row (may be OOB)
  const int gj = blockIdx.x * TILE_C + c - HALO;  // global col (even)
  const bool inImg = ((unsigned)gi < 256u) && ((unsigned)gj < 256u);
  const bool inImgU = ((unsigned)(gi - 1) < 256u) && ((unsigned)gj < 256u);
  const bool inImgL = ((unsigned)gi < 256u) && ((unsigned)(gj - 1) < 256u);
  const int base = blockIdx.z * 65536 + gi * 256 + gj;

  const float alpha0 = rp[0];
  const float alpha1 = rp[1];

  // ---- boundary masks as 0/1 multipliers (thread-constant) ----
  const float mD = (gi != 255) ? 1.f : 0.f;   // has down neighbor (row gi)
  const float mDU = (gi != 256) ? 1.f : 0.f;  // mD of row gi-1
  const float mU = (gi != 0) ? 1.f : 0.f;     // has up neighbor
  v2f mR, mL;
  mR.x = (gj + 0 != 255) ? 1.f : 0.f;
  mR.y = (gj + 1 != 255) ? 1.f : 0.f;
  mL.x = (gj != 0) ? 1.f : 0.f;
  mL.y = 1.f;
  // mR.y of the (c-1) owner thread = ((gj-1)!=255) = 1 always (odd) -> folded.

  // state: one packed v2f per field
  v2f u_, ub_, v1_, v2_, vb1_, vb2_, p1_, p2_, q11_, q22_, q12_, f_;
  // shadow dual state at (r-1, c..c+1) and (r, c-1)
  v2f p1U_, p2U_, q11U_, q22U_, q12U_;
  float p1L_, p2L_, q11L_, q22L_, q12L_;
  p1U_ = 0.f; p2U_ = 0.f; q11U_ = 0.f; q22U_ = 0.f; q12U_ = 0.f;
  p1L_ = 0.f; p2L_ = 0.f; q11L_ = 0.f; q22L_ = 0.f; q12L_ = 0.f;

#define LOADV(dst, src) dst = *reinterpret_cast<const v2f*>((src) + base);
  if (inImg) {
    LOADV(f_, f)
    if (t0 == 0) {
      // PDHG initial state: u = ub = f, everything else zero.
      u_ = f_; ub_ = f_;
      v1_ = 0.f; v2_ = 0.f; vb1_ = 0.f; vb2_ = 0.f;
      p1_ = 0.f; p2_ = 0.f; q11_ = 0.f; q22_ = 0.f; q12_ = 0.f;
    } else {
      LOADV(u_, ug)
      LOADV(ub_, ubg)
      LOADV(v1_, v1g)
      LOADV(v2_, v2g)
      LOADV(vb1_, vb1g)
      LOADV(vb2_, vb2g)
      LOADV(p1_, p1g)
      LOADV(p2_, p2g)
      LOADV(q11_, q11g)
      LOADV(q22_, q22g)
      LOADV(q12_, q12g)
    }
  } else {
    f_ = 0.f; u_ = 0.f; ub_ = 0.f;
    v1_ = 0.f; v2_ = 0.f; vb1_ = 0.f; vb2_ = 0.f;
    p1_ = 0.f; p2_ = 0.f; q11_ = 0.f; q22_ = 0.f; q12_ = 0.f;
  }
#undef LOADV

  if (t0 != 0) {
    // shadow init: p,q of the up-row strip and left-col scalar (stored by
    // their owner blocks last launch).
    if (inImgU) {
      const int bU = base - 256;
      p1U_ = *reinterpret_cast<const v2f*>(p1g + bU);
      p2U_ = *reinterpret_cast<const v2f*>(p2g + bU);
      q11U_ = *reinterpret_cast<const v2f*>(q11g + bU);
      q22U_ = *reinterpret_cast<const v2f*>(q22g + bU);
      q12U_ = *reinterpret_cast<const v2f*>(q12g + bU);
    }
    if (inImgL) {
      const int bL = base - 1;
      p1L_ = p1g[bL];
      p2L_ = p2g[bL];
      q11L_ = q11g[bL];
      q22L_ = q22g[bL];
      q12L_ = q12g[bL];
    }
  }

  // Loop-invariant hoist (bit-exact: identical expression, computed once).
  const v2f fI = kTau * f_;

  for (int t = 0; t < HALO; ++t) {
    float* ubS = (t & 1) ? ubB1 : ubB0;
    float* vbS = (t & 1) ? vbB1 : vbB0;
    // Row-wise trapezoid gating (validated R14/R20).
    const bool pubD = (r >= t) && (r <= 31 - t);
    const bool actD = (r >= t) && (r <= 30 - t);
    const bool actP = (r >= t + 1) && (r <= 30 - t);

    // ---- publish dual-input halos: ub (b64), vb pair (b128) ----
    if (pubD) {
      *reinterpret_cast<v2f*>(ubS + rc) = ub_;
      float4 vp;
      vp.x = vb1_.x; vp.y = vb2_.x; vp.z = vb1_.y; vp.w = vb2_.y;
      *reinterpret_cast<float4*>(vbS + 2 * rc) = vp;
    }
    __syncthreads();  // the ONLY barrier this iteration

    if (actD) {
      // ---- LDS reads: own dual + up-row shadow + left-col shadow ----
      const float ubX = ubS[rc + 2];
      const v2f vbX = *reinterpret_cast<const v2f*>(vbS + 2 * (rc + 2));
      const v2f ubD = *reinterpret_cast<const v2f*>(ubS + rc + RC);
      const float4 vd = ld4(vbS + 2 * (rc + RC));
      const v2f ubU = *reinterpret_cast<const v2f*>(ubS + rc - RC);
      const float ubUX = ubS[rc - RC + 2];
      const float4 vu = ld4(vbS + 2 * (rc - RC));
      const v2f vbUX = *reinterpret_cast<const v2f*>(vbS + 2 * (rc - RC + 2));
      const float ubL = ubS[rc - 1];
      const float ubDL = ubS[rc + RC - 1];
      const v2f vbL = *reinterpret_cast<const v2f*>(vbS + 2 * (rc - 1));
      const v2f vbDL = *reinterpret_cast<const v2f*>(vbS + 2 * (rc + RC - 1));

      v2f vb1D, vb2D;
      vb1D.x = vd.x; vb1D.y = vd.z;
      vb2D.x = vd.y; vb2D.y = vd.w;
      v2f vb1U, vb2U;
      vb1U.x = vu.x; vb1U.y = vu.z;
      vb2U.x = vu.y; vb2U.y = vu.w;

      // ---- own dual ascent + projections (identical to R14) ----
      v2f ubr, vb1r, vb2r;  // right-shifted (element e+1)
      ubr.x = ub_.y;   ubr.y = ubX;
      vb1r.x = vb1_.y; vb1r.y = vbX.x;
      vb2r.x = vb2_.y; vb2r.y = vbX.y;

      const v2f du1 = mD * (ubD - ub_);
      const v2f du2 = mR * (ubr - ub_);
      const v2f pn1 = p1_ + kSigma * (du1 - vb1_);
      const v2f pn2 = p2_ + kSigma * (du2 - vb2_);
      const v2f n2p = pn1 * pn1 + pn2 * pn2;
      v2f sp;
      sp.x = fminf(1.f, alpha1 * __builtin_amdgcn_rsqf(n2p.x));
      sp.y = fminf(1.f, alpha1 * __builtin_amdgcn_rsqf(n2p.y));
      p1_ = pn1 * sp;
      p2_ = pn2 * sp;

      const v2f e11 = mD * (vb1D - vb1_);
      const v2f e22 = mR * (vb2r - vb2_);
      const v2f e12 = 0.5f * (mR * (vb1r - vb1_) + mD * (vb2D - vb2_));
      const v2f qn1 = q11_ + kSigma * e11;
      const v2f qn2 = q22_ + kSigma * e22;
      const v2f qn3 = q12_ + kSigma * e12;
      const v2f n2q = qn1 * qn1 + qn2 * qn2 + 2.f * (qn3 * qn3);
      v2f sq;
      sq.x = fminf(1.f, alpha0 * __builtin_amdgcn_rsqf(n2q.x));
      sq.y = fminf(1.f, alpha0 * __builtin_amdgcn_rsqf(n2q.y));
      q11_ = qn1 * sq;
      q22_ = qn2 * sq;
      q12_ = qn3 * sq;

      // ---- shadow dual at (r-1, c..c+1): replicate the up thread ----
      // its down-neighbor inputs are OUR registers (true ub/vb at row r).
      v2f ubrU, vb1rU, vb2rU;
      ubrU.x = ubU.y;   ubrU.y = ubUX;
      vb1rU.x = vb1U.y; vb1rU.y = vbUX.x;
      vb2rU.x = vb2U.y; vb2rU.y = vbUX.y;

      const v2f du1U = mDU * (ub_ - ubU);
      const v2f du2U = mR * (ubrU - ubU);
      const v2f pn1U = p1U_ + kSigma * (du1U - vb1U);
      const v2f pn2U = p2U_ + kSigma * (du2U - vb2U);
      const v2f n2pU = pn1U * pn1U + pn2U * pn2U;
      v2f spU;
      spU.x = fminf(1.f, alpha1 * __builtin_amdgcn_rsqf(n2pU.x));
      spU.y = fminf(1.f, alpha1 * __builtin_amdgcn_rsqf(n2pU.y));
      p1U_ = pn1U * spU;
      p2U_ = pn2U * spU;

      const v2f e11U = mDU * (vb1_ - vb1U);
      const v2f e22U = mR * (vb2rU - vb2U);
      const v2f e12U = 0.5f * (mR * (vb1rU - vb1U) + mDU * (vb2_ - vb2U));
      const v2f qn1U = q11U_ + kSigma * e11U;
      const v2f qn2U = q22U_ + kSigma * e22U;
      const v2f qn3U = q12U_ + kSigma * e12U;
      const v2f n2qU = qn1U * qn1U + qn2U * qn2U + 2.f * (qn3U * qn3U);
      v2f sqU;
      sqU.x = fminf(1.f, alpha0 * __builtin_amdgcn_rsqf(n2qU.x));
      sqU.y = fminf(1.f, alpha0 * __builtin_amdgcn_rsqf(n2qU.y));
      q11U_ = qn1U * sqU;
      q22U_ = qn2U * sqU;
      q12U_ = qn3U * sqU;

      // ---- shadow dual at (r, c-1): replicate the left thread's .y ----
      // its mR.y = ((gj-1)!=255) = 1 (odd col) -> multiplies folded (x*1==x);
      // its right-neighbor inputs are OUR .x registers.
      const float du1L = mD * (ubDL - ubL);
      const float du2L = ub_.x - ubL;
      const float pn1L = p1L_ + kSigma * (du1L - vbL.x);
      const float pn2L = p2L_ + kSigma * (du2L - vbL.y);
      const float n2pL = pn1L * pn1L + pn2L * pn2L;
      const float spL = fminf(1.f, alpha1 * __builtin_amdgcn_rsqf(n2pL));
      p1L_ = pn1L * spL;
      p2L_ = pn2L * spL;

      const float e11L = mD * (vbDL.x - vbL.x);
      const float e22L = vb2_.x - vbL.y;
      const float e12L = 0.5f * ((vb1_.x - vbL.x) + mD * (vbDL.y - vbL.y));
      const float qn1L = q11L_ + kSigma * e11L;
      const float qn2L = q22L_ + kSigma * e22L;
      const float qn3L = q12L_ + kSigma * e12L;
      const float n2qL = qn1L * qn1L + qn2L * qn2L + 2.f * (qn3L * qn3L);
      const float sqL = fminf(1.f, alpha0 * __builtin_amdgcn_rsqf(n2qL));
      q11L_ = qn1L * sqL;
      q22L_ = qn2L * sqL;
      q12L_ = qn3L * sqL;
    }

    if (actP) {
      // ---- primal descent + over-relaxation (neighbors from shadows) ----
      v2f p2l, q22l, q12l;  // left-shifted (element e-1)
      p2l.x = p2L_;   p2l.y = p2_.x;
      q22l.x = q22L_; q22l.y = q22_.x;
      q12l.x = q12L_; q12l.y = q12_.x;

      const v2f divp = mD * p1_ + mR * p2_ - (mU * p1U_ + mL * p2l);
      const v2f un = (u_ + kTau * divp + fI) * kInv1pTau;
      ub_ = 2.f * un - u_;
      u_ = un;

      const v2f c1 = mD * q11_ + mR * q12_ - (mU * q11U_ + mL * q12l);
      const v2f c2 = mD * q12_ + mR * q22_ - (mU * q12U_ + mL * q22l);
      const v2f v1n = v1_ + kTau * (p1_ + c1);
      const v2f v2n = v2_ + kTau * (p2_ + c2);
      vb1_ = 2.f * v1n - v1_;
      v1_ = v1n;
      vb2_ = 2.f * v2n - v2_;
      v2_ = v2n;
    }
  }

  // ---- store interior 16x32 (exact after 8 iters) ----
  if (r >= HALO && r < HALO + TILE_R && c >= HALO && c < HALO + TILE_C) {
#define STOREV(src, dst) *reinterpret_cast<v2f*>((dst) + base) = src;
    STOREV(u_, ug)
    if (t0 != NLAUNCH - 1) {  // ws is dead after the final launch
      STOREV(ub_, ubg)
      STOREV(v1_, v1g)
      STOREV(v2_, v2g)
      STOREV(vb1_, vb1g)
      STOREV(vb2_, vb2g)
      STOREV(p1_, p1g)
      STOREV(p2_, p2g)
      STOREV(q11_, q11g)
      STOREV(q22_, q22g)
      STOREV(q12_, q12g)
    }
#undef STOREV
  }
}

}  // namespace

extern "C" void kernel_launch(void* const* d_in, const int* in_sizes, int n_in,
                              void* d_out, int out_size, void* d_ws,
                              size_t ws_size, hipStream_t stream) {
  const float* f = (const float*)d_in[0];
  const float* rp = (const float*)d_in[1];  // [alpha0, alpha1]
  // d_in[2] is T = 128 (fixed; trip count must be static for graph capture).

  float* u = (float*)d_out;
  float* ws = (float*)d_ws;

  dim3 grid(256 / TILE_C, 256 / TILE_R, 2);  // 8 x 16 x 2 = 256 blocks
  for (int t = 0; t < NLAUNCH; ++t) {        // 16 launches x 8 iterations
    hipLaunchKernelGGL(tgv8_kernel, grid, dim3(NTHREADS), 0, stream, f, rp, u,
                       ws, t);
  }
}

// Round 9
// 205.887 us; speedup vs baseline: 1.5293x; 1.5293x over previous
//
#include <hip/hip_runtime.h>
#include <math.h>

// TGV-2 PDHG, B=2, H=W=256, T=128.
// R22 = R20 base (252.9us, absmax 7.45e-9) + XCD-aware block swizzle (T1).
// Model after R11/R14/R19/R20/R21: per-iter time = 2 x (barrier + LDS
// round-trip LATENCY floor) + small chain term; insensitive to op count
// (R20: -25% ops neutral), byte count (R12), off-path work (R14), and made
// WORSE by chain-lengthening barrier elimination (R21: +25%). Remaining
// unexplained term: fixed ~7.6us/launch (from R19's work-scaling fit), a
// large slice of which is the 11-field, ~25MB/launch state handoff. With
// linear blockIdx the HW round-robins consecutive blocks over 8 XCDs, so
// halo reloads (written by NEIGHBOR blocks last launch) are cross-XCD ->
// LLC/HBM every launch. Swizzle j=(i%8)*32+i/8 (bijective, 256%8==0) gives
// each XCD a contiguous 64-row x 256-col slab of one batch -> own-tile and
// most halo reloads become same-XCD L2 hits (4MB/XCD, 34TB/s). Only
// slab-edge block-rows still cross. Pure index permutation -> output
// bit-identical (absmax must stay exactly 7.450581e-09).
// Everything else identical to R20: 16 launches x 8 trapezoid iters, region
// 32x48 (tile 16x32, halo 8), 256 blocks (1/CU), 768 threads (12 waves),
// packed v2f math, rsq+min projection, row gating, interior-maskless body
// (bit-exact), tau*f hoist, init folded into launch 0, final launch stores
// only u.

namespace {

typedef float v2f __attribute__((ext_vector_type(2)));

constexpr int kN = 2 * 256 * 256;
constexpr float kTau = 0.28867513459481287f;  // 1/sqrt(12) (f32)
constexpr float kSigma = kTau;
constexpr float kInv1pTau = 1.0f / (1.0f + kTau);

constexpr int RR = 32;          // region rows (H)
constexpr int RC = 48;          // region cols (W)
constexpr int A = RR * RC;      // 1536 floats per LDS array
constexpr int PAD = 64;         // rim-overread safety pads (front/back)
constexpr int TILE_R = 16;
constexpr int TILE_C = 32;
constexpr int HALO = 8;         // = iterations per launch
constexpr int NLAUNCH = 128 / HALO;      // 16
constexpr int NTHREADS = RR * (RC / 2);  // 768 = 12 waves

__device__ __forceinline__ float4 ld4(const float* p) {
  return *reinterpret_cast<const float4*>(p);
}

// The 8-iteration trapezoid loop. M=true: boundary blocks (image-edge masks
// as 0/1 multipliers). M=false: interior blocks — every mask is 1.0,
// multiplies removed (bit-exact: x*1.0f == x, no reassociation).
template <bool M>
__device__ __forceinline__ void run8(
    float* ubS, float* vbS, float* p1S, float* p2S, float* q11S, float* q22S,
    float* q12S, const int rc, const int r, const float alpha0,
    const float alpha1, const float mD, const float mU, const v2f mR,
    const v2f mL, const v2f fI, v2f& u_, v2f& ub_, v2f& v1_, v2f& v2_,
    v2f& vb1_, v2f& vb2_, v2f& p1_, v2f& p2_, v2f& q11_, v2f& q22_,
    v2f& q12_) {
  for (int t = 0; t < HALO; ++t) {
    // Active-set gating (row-wise, wave-granular) — measured-neutral, never
    // harmful; rows outside the sets are never read by valid outputs.
    const bool pubD = (r >= t) && (r <= 31 - t);
    const bool actD = (r >= t) && (r <= 30 - t);
    const bool actP = (r >= t + 1) && (r <= 30 - t);

    // ---- publish dual halos: ub (b64), vb pair (b128) ----
    if (pubD) {
      *reinterpret_cast<v2f*>(ubS + rc) = ub_;
      float4 vp;
      vp.x = vb1_.x; vp.y = vb2_.x; vp.z = vb1_.y; vp.w = vb2_.y;
      *reinterpret_cast<float4*>(vbS + 2 * rc) = vp;
    }
    __syncthreads();

    if (actD) {
      // ---- dual ascent + projections ----
      const float ubX = ubS[rc + 2];  // right-edge scalar neighbor
      const v2f vbX = *reinterpret_cast<const v2f*>(vbS + 2 * (rc + 2));
      const v2f ubD = *reinterpret_cast<const v2f*>(ubS + rc + RC);
      const float4 vd = ld4(vbS + 2 * (rc + RC));
      v2f vb1D, vb2D;
      vb1D.x = vd.x; vb1D.y = vd.z;
      vb2D.x = vd.y; vb2D.y = vd.w;

      v2f ubr, vb1r, vb2r;  // right-shifted (element e+1)
      ubr.x = ub_.y;   ubr.y = ubX;
      vb1r.x = vb1_.y; vb1r.y = vbX.x;
      vb2r.x = vb2_.y; vb2r.y = vbX.y;

      // p update
      const v2f du1 = M ? mD * (ubD - ub_) : (ubD - ub_);
      const v2f du2 = M ? mR * (ubr - ub_) : (ubr - ub_);
      const v2f pn1 = p1_ + kSigma * (du1 - vb1_);
      const v2f pn2 = p2_ + kSigma * (du2 - vb2_);
      const v2f n2p = pn1 * pn1 + pn2 * pn2;
      v2f sp;
      sp.x = fminf(1.f, alpha1 * __builtin_amdgcn_rsqf(n2p.x));
      sp.y = fminf(1.f, alpha1 * __builtin_amdgcn_rsqf(n2p.y));
      p1_ = pn1 * sp;
      p2_ = pn2 * sp;

      // q update (e11, e22, e12)
      const v2f e11 = M ? mD * (vb1D - vb1_) : (vb1D - vb1_);
      const v2f e22 = M ? mR * (vb2r - vb2_) : (vb2r - vb2_);
      const v2f e12 = M ? 0.5f * (mR * (vb1r - vb1_) + mD * (vb2D - vb2_))
                        : 0.5f * ((vb1r - vb1_) + (vb2D - vb2_));
      const v2f qn1 = q11_ + kSigma * e11;
      const v2f qn2 = q22_ + kSigma * e22;
      const v2f qn3 = q12_ + kSigma * e12;
      const v2f n2q = qn1 * qn1 + qn2 * qn2 + 2.f * (qn3 * qn3);
      v2f sq;
      sq.x = fminf(1.f, alpha0 * __builtin_amdgcn_rsqf(n2q.x));
      sq.y = fminf(1.f, alpha0 * __builtin_amdgcn_rsqf(n2q.y));
      q11_ = qn1 * sq;
      q22_ = qn2 * sq;
      q12_ = qn3 * sq;

      // ---- publish primal halos (new p, q) ----
      *reinterpret_cast<v2f*>(p1S + rc) = p1_;
      *reinterpret_cast<v2f*>(p2S + rc) = p2_;
      *reinterpret_cast<v2f*>(q11S + rc) = q11_;
      *reinterpret_cast<v2f*>(q22S + rc) = q22_;
      *reinterpret_cast<v2f*>(q12S + rc) = q12_;
    }
    __syncthreads();

    if (actP) {
      // ---- primal descent + over-relaxation ----
      const v2f p1U = *reinterpret_cast<const v2f*>(p1S + rc - RC);
      const v2f q11U = *reinterpret_cast<const v2f*>(q11S + rc - RC);
      const v2f q12U = *reinterpret_cast<const v2f*>(q12S + rc - RC);
      const float p2Ls = p2S[rc - 1];   // left-edge scalar neighbors
      const float q22Ls = q22S[rc - 1];
      const float q12Ls = q12S[rc - 1];

      v2f p2l, q22l, q12l;  // left-shifted (element e-1)
      p2l.x = p2Ls;   p2l.y = p2_.x;
      q22l.x = q22Ls; q22l.y = q22_.x;
      q12l.x = q12Ls; q12l.y = q12_.x;

      const v2f divp = M ? (mD * p1_ + mR * p2_ - (mU * p1U + mL * p2l))
                         : (p1_ + p2_ - (p1U + p2l));
      const v2f un = (u_ + kTau * divp + fI) * kInv1pTau;
      ub_ = 2.f * un - u_;
      u_ = un;

      const v2f c1 = M ? (mD * q11_ + mR * q12_ - (mU * q11U + mL * q12l))
                       : (q11_ + q12_ - (q11U + q12l));
      const v2f c2 = M ? (mD * q12_ + mR * q22_ - (mU * q12U + mL * q22l))
                       : (q12_ + q22_ - (q12U + q22l));
      const v2f v1n = v1_ + kTau * (p1_ + c1);
      const v2f v2n = v2_ + kTau * (p2_ + c2);
      vb1_ = 2.f * v1n - v1_;
      v1_ = v1n;
      vb2_ = 2.f * v2n - v2_;
      v2_ = v2n;
    }
  }
}

// ws layout: 10 arrays of kN floats: ub, v1, v2, vb1, vb2, p1, p2, q11, q22, q12
__global__ __launch_bounds__(NTHREADS, 3) void tgv8_kernel(
    const float* __restrict__ f, const float* __restrict__ rp,
    float* __restrict__ ug, float* __restrict__ ws, int t0) {
  float* ubg = ws + 0 * kN;
  float* v1g = ws + 1 * kN;
  float* v2g = ws + 2 * kN;
  float* vb1g = ws + 3 * kN;
  float* vb2g = ws + 4 * kN;
  float* p1g = ws + 5 * kN;
  float* p2g = ws + 6 * kN;
  float* q11g = ws + 7 * kN;
  float* q22g = ws + 8 * kN;
  float* q12g = ws + 9 * kN;

  // LDS: ub (A) + vb-pair (2A) + p1,p2,q11,q22,q12 (5A) = 8A floats
  __shared__ __align__(16) float smem[PAD + 8 * A + PAD];
  float* ubS = smem + PAD;
  float* vbS = ubS + A;       // interleaved [vb1, vb2] per pixel, 2A floats
  float* p1S = vbS + 2 * A;
  float* p2S = p1S + A;
  float* q11S = p2S + A;
  float* q22S = q11S + A;
  float* q12S = q22S + A;

  // ---- XCD-aware block swizzle (T1) ----
  // HW round-robins linear workgroup id over 8 XCDs. Remap so XCD k owns a
  // contiguous 64-row x 256-col slab of one batch: j = (i%8)*32 + i/8
  // (bijective on [0,256)). Launch-to-launch halo reloads become same-XCD
  // L2 hits for all but slab-edge block-rows.
  const int lin = blockIdx.x + 8 * (blockIdx.y + 16 * blockIdx.z);
  const int j = ((lin & 7) << 5) | (lin >> 3);
  const int bz = j >> 7;         // batch
  const int by = (j >> 3) & 15;  // tile row
  const int bx = j & 7;          // tile col

  const int tid = threadIdx.x;
  const int r = tid / 24;        // region row 0..31
  const int c = (tid % 24) * 2;  // region col (float2-aligned)
  const int rc = r * RC + c;

  const int gi = by * TILE_R + r - HALO;  // global row (may be OOB)
  const int gj = bx * TILE_C + c - HALO;  // global col (even)
  const bool inImg = ((unsigned)gi < 256u) && ((unsigned)gj < 256u);
  const int base = bz * 65536 + gi * 256 + gj;

  // Interior block: whole region inside (0,255) in both dims -> masks all 1.
  const bool interior = (bx >= 1) && (bx <= 6) && (by >= 1) && (by <= 14);

  const float alpha0 = rp[0];
  const float alpha1 = rp[1];

  // ---- boundary masks as 0/1 multipliers (thread-constant) ----
  const float mD = (gi != 255) ? 1.f : 0.f;  // has down neighbor (H fwd)
  const float mU = (gi != 0) ? 1.f : 0.f;    // has up neighbor (H bwd)
  v2f mR, mL;
  mR.x = (gj + 0 != 255) ? 1.f : 0.f;
  mR.y = (gj + 1 != 255) ? 1.f : 0.f;
  mL.x = (gj != 0) ? 1.f : 0.f;
  mL.y = 1.f;

  // state: one packed v2f per field
  v2f u_, ub_, v1_, v2_, vb1_, vb2_, p1_, p2_, q11_, q22_, q12_, f_;

#define LOADV(dst, src) dst = *reinterpret_cast<const v2f*>((src) + base);
  if (inImg) {
    LOADV(f_, f)
    if (t0 == 0) {
      // PDHG initial state: u = ub = f, everything else zero.
      u_ = f_; ub_ = f_;
      v1_ = 0.f; v2_ = 0.f; vb1_ = 0.f; vb2_ = 0.f;
      p1_ = 0.f; p2_ = 0.f; q11_ = 0.f; q22_ = 0.f; q12_ = 0.f;
    } else {
      LOADV(u_, ug)
      LOADV(ub_, ubg)
      LOADV(v1_, v1g)
      LOADV(v2_, v2g)
      LOADV(vb1_, vb1g)
      LOADV(vb2_, vb2g)
      LOADV(p1_, p1g)
      LOADV(p2_, p2g)
      LOADV(q11_, q11g)
      LOADV(q22_, q22g)
      LOADV(q12_, q12g)
    }
  } else {
    f_ = 0.f; u_ = 0.f; ub_ = 0.f;
    v1_ = 0.f; v2_ = 0.f; vb1_ = 0.f; vb2_ = 0.f;
    p1_ = 0.f; p2_ = 0.f; q11_ = 0.f; q22_ = 0.f; q12_ = 0.f;
  }
#undef LOADV

  // Loop-invariant hoist (bit-exact: identical expression, computed once).
  const v2f fI = kTau * f_;

  if (interior) {
    run8<false>(ubS, vbS, p1S, p2S, q11S, q22S, q12S, rc, r, alpha0, alpha1,
                mD, mU, mR, mL, fI, u_, ub_, v1_, v2_, vb1_, vb2_, p1_, p2_,
                q11_, q22_, q12_);
  } else {
    run8<true>(ubS, vbS, p1S, p2S, q11S, q22S, q12S, rc, r, alpha0, alpha1,
               mD, mU, mR, mL, fI, u_, ub_, v1_, v2_, vb1_, vb2_, p1_, p2_,
               q11_, q22_, q12_);
  }

  // ---- store interior 16x32 (exact after 8 iters) ----
  if (r >= HALO && r < HALO + TILE_R && c >= HALO && c < HALO + TILE_C) {
#define STOREV(src, dst) *reinterpret_cast<v2f*>((dst) + base) = src;
    STOREV(u_, ug)
    if (t0 != NLAUNCH - 1) {  // ws is dead after the final launch
      STOREV(ub_, ubg)
      STOREV(v1_, v1g)
      STOREV(v2_, v2g)
      STOREV(vb1_, vb1g)
      STOREV(vb2_, vb2g)
      STOREV(p1_, p1g)
      STOREV(p2_, p2g)
      STOREV(q11_, q11g)
      STOREV(q22_, q22g)
      STOREV(q12_, q12g)
    }
#undef STOREV
  }
}

}  // namespace

extern "C" void kernel_launch(void* const* d_in, const int* in_sizes, int n_in,
                              void* d_out, int out_size, void* d_ws,
                              size_t ws_size, hipStream_t stream) {
  const float* f = (const float*)d_in[0];
  const float* rp = (const float*)d_in[1];  // [alpha0, alpha1]
  // d_in[2] is T = 128 (fixed; trip count must be static for graph capture).

  float* u = (float*)d_out;
  float* ws = (float*)d_ws;

  dim3 grid(256 / TILE_C, 256 / TILE_R, 2);  // 8 x 16 x 2 = 256 blocks
  for (int t = 0; t < NLAUNCH; ++t) {        // 16 launches x 8 iterations
    hipLaunchKernelGGL(tgv8_kernel, grid, dim3(NTHREADS), 0, stream, f, rp, u,
                       ws, t);
  }
}

// Round 10
// 199.573 us; speedup vs baseline: 1.5776x; 1.0316x over previous
//
#include <hip/hip_runtime.h>
#include <math.h>

// TGV-2 PDHG, B=2, H=W=256, T=128.
// R23 = R22 (205.9us, absmax 7.45e-9; XCD swizzle win confirmed the
// launch-boundary I/O theory) + paired-field ws layout.
// Budget model: Total = 128us exec floor (1us/iter x 128, two-barrier
// latency/issue) + 16 x F, F ~ 4.9us/launch fixed (launch ~2us + state
// handoff). This round halves the handoff instruction count: the 10 ws
// fields are interleaved pairwise per pixel — (vb1,vb2),(p1,p2),(q11,q22),
// (ub,q12),(v1,v2) — each pair one float4 at 2*base (16B aligned, base
// even). Loads 12->7 (5xb128 + u from ug + f), stores 11->6. Same values,
// same arithmetic -> output bit-identical (absmax must stay exactly
// 7.450581e-09). Dual-phase fields (ub,vb,p,q) load first; u/f (primal-only)
// drain under later waitcnts.
// NOTE (R20 errata): R20's interior-maskless probe was NULL, not a
// refutation of issue-bound — boundary blocks (unchanged) pin the dispatch.
// Kept because it's free.
// Everything else = R22: 16 launches x 8 trapezoid iters, region 32x48
// (tile 16x32, halo 8), 256 blocks (1/CU), 768 threads (12 waves), packed
// v2f math, rsq+min projection, row gating, interior-maskless body,
// tau*f hoist, XCD swizzle j=(i%8)*32+i/8, init folded into launch 0,
// final launch stores only u.

namespace {

typedef float v2f __attribute__((ext_vector_type(2)));

constexpr int kN = 2 * 256 * 256;
constexpr float kTau = 0.28867513459481287f;  // 1/sqrt(12) (f32)
constexpr float kSigma = kTau;
constexpr float kInv1pTau = 1.0f / (1.0f + kTau);

constexpr int RR = 32;          // region rows (H)
constexpr int RC = 48;          // region cols (W)
constexpr int A = RR * RC;      // 1536 floats per LDS array
constexpr int PAD = 64;         // rim-overread safety pads (front/back)
constexpr int TILE_R = 16;
constexpr int TILE_C = 32;
constexpr int HALO = 8;         // = iterations per launch
constexpr int NLAUNCH = 128 / HALO;      // 16
constexpr int NTHREADS = RR * (RC / 2);  // 768 = 12 waves

__device__ __forceinline__ float4 ld4(const float* p) {
  return *reinterpret_cast<const float4*>(p);
}

// The 8-iteration trapezoid loop. M=true: boundary blocks (image-edge masks
// as 0/1 multipliers). M=false: interior blocks — every mask is 1.0,
// multiplies removed (bit-exact: x*1.0f == x, no reassociation).
template <bool M>
__device__ __forceinline__ void run8(
    float* ubS, float* vbS, float* p1S, float* p2S, float* q11S, float* q22S,
    float* q12S, const int rc, const int r, const float alpha0,
    const float alpha1, const float mD, const float mU, const v2f mR,
    const v2f mL, const v2f fI, v2f& u_, v2f& ub_, v2f& v1_, v2f& v2_,
    v2f& vb1_, v2f& vb2_, v2f& p1_, v2f& p2_, v2f& q11_, v2f& q22_,
    v2f& q12_) {
  for (int t = 0; t < HALO; ++t) {
    // Active-set gating (row-wise, wave-granular) — measured-neutral, never
    // harmful; rows outside the sets are never read by valid outputs.
    const bool pubD = (r >= t) && (r <= 31 - t);
    const bool actD = (r >= t) && (r <= 30 - t);
    const bool actP = (r >= t + 1) && (r <= 30 - t);

    // ---- publish dual halos: ub (b64), vb pair (b128) ----
    if (pubD) {
      *reinterpret_cast<v2f*>(ubS + rc) = ub_;
      float4 vp;
      vp.x = vb1_.x; vp.y = vb2_.x; vp.z = vb1_.y; vp.w = vb2_.y;
      *reinterpret_cast<float4*>(vbS + 2 * rc) = vp;
    }
    __syncthreads();

    if (actD) {
      // ---- dual ascent + projections ----
      const float ubX = ubS[rc + 2];  // right-edge scalar neighbor
      const v2f vbX = *reinterpret_cast<const v2f*>(vbS + 2 * (rc + 2));
      const v2f ubD = *reinterpret_cast<const v2f*>(ubS + rc + RC);
      const float4 vd = ld4(vbS + 2 * (rc + RC));
      v2f vb1D, vb2D;
      vb1D.x = vd.x; vb1D.y = vd.z;
      vb2D.x = vd.y; vb2D.y = vd.w;

      v2f ubr, vb1r, vb2r;  // right-shifted (element e+1)
      ubr.x = ub_.y;   ubr.y = ubX;
      vb1r.x = vb1_.y; vb1r.y = vbX.x;
      vb2r.x = vb2_.y; vb2r.y = vbX.y;

      // p update
      const v2f du1 = M ? mD * (ubD - ub_) : (ubD - ub_);
      const v2f du2 = M ? mR * (ubr - ub_) : (ubr - ub_);
      const v2f pn1 = p1_ + kSigma * (du1 - vb1_);
      const v2f pn2 = p2_ + kSigma * (du2 - vb2_);
      const v2f n2p = pn1 * pn1 + pn2 * pn2;
      v2f sp;
      sp.x = fminf(1.f, alpha1 * __builtin_amdgcn_rsqf(n2p.x));
      sp.y = fminf(1.f, alpha1 * __builtin_amdgcn_rsqf(n2p.y));
      p1_ = pn1 * sp;
      p2_ = pn2 * sp;

      // q update (e11, e22, e12)
      const v2f e11 = M ? mD * (vb1D - vb1_) : (vb1D - vb1_);
      const v2f e22 = M ? mR * (vb2r - vb2_) : (vb2r - vb2_);
      const v2f e12 = M ? 0.5f * (mR * (vb1r - vb1_) + mD * (vb2D - vb2_))
                        : 0.5f * ((vb1r - vb1_) + (vb2D - vb2_));
      const v2f qn1 = q11_ + kSigma * e11;
      const v2f qn2 = q22_ + kSigma * e22;
      const v2f qn3 = q12_ + kSigma * e12;
      const v2f n2q = qn1 * qn1 + qn2 * qn2 + 2.f * (qn3 * qn3);
      v2f sq;
      sq.x = fminf(1.f, alpha0 * __builtin_amdgcn_rsqf(n2q.x));
      sq.y = fminf(1.f, alpha0 * __builtin_amdgcn_rsqf(n2q.y));
      q11_ = qn1 * sq;
      q22_ = qn2 * sq;
      q12_ = qn3 * sq;

      // ---- publish primal halos (new p, q) ----
      *reinterpret_cast<v2f*>(p1S + rc) = p1_;
      *reinterpret_cast<v2f*>(p2S + rc) = p2_;
      *reinterpret_cast<v2f*>(q11S + rc) = q11_;
      *reinterpret_cast<v2f*>(q22S + rc) = q22_;
      *reinterpret_cast<v2f*>(q12S + rc) = q12_;
    }
    __syncthreads();

    if (actP) {
      // ---- primal descent + over-relaxation ----
      const v2f p1U = *reinterpret_cast<const v2f*>(p1S + rc - RC);
      const v2f q11U = *reinterpret_cast<const v2f*>(q11S + rc - RC);
      const v2f q12U = *reinterpret_cast<const v2f*>(q12S + rc - RC);
      const float p2Ls = p2S[rc - 1];   // left-edge scalar neighbors
      const float q22Ls = q22S[rc - 1];
      const float q12Ls = q12S[rc - 1];

      v2f p2l, q22l, q12l;  // left-shifted (element e-1)
      p2l.x = p2Ls;   p2l.y = p2_.x;
      q22l.x = q22Ls; q22l.y = q22_.x;
      q12l.x = q12Ls; q12l.y = q12_.x;

      const v2f divp = M ? (mD * p1_ + mR * p2_ - (mU * p1U + mL * p2l))
                         : (p1_ + p2_ - (p1U + p2l));
      const v2f un = (u_ + kTau * divp + fI) * kInv1pTau;
      ub_ = 2.f * un - u_;
      u_ = un;

      const v2f c1 = M ? (mD * q11_ + mR * q12_ - (mU * q11U + mL * q12l))
                       : (q11_ + q12_ - (q11U + q12l));
      const v2f c2 = M ? (mD * q12_ + mR * q22_ - (mU * q12U + mL * q22l))
                       : (q12_ + q22_ - (q12U + q22l));
      const v2f v1n = v1_ + kTau * (p1_ + c1);
      const v2f v2n = v2_ + kTau * (p2_ + c2);
      vb1_ = 2.f * v1n - v1_;
      v1_ = v1n;
      vb2_ = 2.f * v2n - v2_;
      v2_ = v2n;
    }
  }
}

// ws layout: 5 pair-arrays of 2*kN floats, interleaved per pixel:
//   pr0=(vb1,vb2) pr1=(p1,p2) pr2=(q11,q22) pr3=(ub,q12) pr4=(v1,v2)
// u lives in ug (d_out) as before; f is the read-only input.
__global__ __launch_bounds__(NTHREADS, 3) void tgv8_kernel(
    const float* __restrict__ f, const float* __restrict__ rp,
    float* __restrict__ ug, float* __restrict__ ws, int t0) {
  float* pr0 = ws + 0 * 2 * kN;  // vb1, vb2
  float* pr1 = ws + 1 * 2 * kN;  // p1, p2
  float* pr2 = ws + 2 * 2 * kN;  // q11, q22
  float* pr3 = ws + 3 * 2 * kN;  // ub, q12
  float* pr4 = ws + 4 * 2 * kN;  // v1, v2

  // LDS: ub (A) + vb-pair (2A) + p1,p2,q11,q22,q12 (5A) = 8A floats
  __shared__ __align__(16) float smem[PAD + 8 * A + PAD];
  float* ubS = smem + PAD;
  float* vbS = ubS + A;       // interleaved [vb1, vb2] per pixel, 2A floats
  float* p1S = vbS + 2 * A;
  float* p2S = p1S + A;
  float* q11S = p2S + A;
  float* q22S = q11S + A;
  float* q12S = q22S + A;

  // ---- XCD-aware block swizzle (T1, validated R22: -47us) ----
  const int lin = blockIdx.x + 8 * (blockIdx.y + 16 * blockIdx.z);
  const int j = ((lin & 7) << 5) | (lin >> 3);
  const int bz = j >> 7;         // batch
  const int by = (j >> 3) & 15;  // tile row
  const int bx = j & 7;          // tile col

  const int tid = threadIdx.x;
  const int r = tid / 24;        // region row 0..31
  const int c = (tid % 24) * 2;  // region col (float2-aligned)
  const int rc = r * RC + c;

  const int gi = by * TILE_R + r - HALO;  // global row (may be OOB)
  const int gj = bx * TILE_C + c - HALO;  // global col (even)
  const bool inImg = ((unsigned)gi < 256u) && ((unsigned)gj < 256u);
  const int base = bz * 65536 + gi * 256 + gj;

  // Interior block: whole region inside (0,255) in both dims -> masks all 1.
  const bool interior = (bx >= 1) && (bx <= 6) && (by >= 1) && (by <= 14);

  const float alpha0 = rp[0];
  const float alpha1 = rp[1];

  // ---- boundary masks as 0/1 multipliers (thread-constant) ----
  const float mD = (gi != 255) ? 1.f : 0.f;  // has down neighbor (H fwd)
  const float mU = (gi != 0) ? 1.f : 0.f;    // has up neighbor (H bwd)
  v2f mR, mL;
  mR.x = (gj + 0 != 255) ? 1.f : 0.f;
  mR.y = (gj + 1 != 255) ? 1.f : 0.f;
  mL.x = (gj != 0) ? 1.f : 0.f;
  mL.y = 1.f;

  // state: one packed v2f per field
  v2f u_, ub_, v1_, v2_, vb1_, vb2_, p1_, p2_, q11_, q22_, q12_, f_;

// paired load/store: [A(x),B(x),A(x+1),B(x+1)] at 2*base (16B aligned)
#define LOADP(va, vb, src)                    \
  {                                           \
    const float4 t4 = ld4((src) + 2 * base);  \
    va.x = t4.x; vb.x = t4.y;                 \
    va.y = t4.z; vb.y = t4.w;                 \
  }
  if (inImg) {
    f_ = *reinterpret_cast<const v2f*>(f + base);
    if (t0 == 0) {
      // PDHG initial state: u = ub = f, everything else zero.
      u_ = f_; ub_ = f_;
      v1_ = 0.f; v2_ = 0.f; vb1_ = 0.f; vb2_ = 0.f;
      p1_ = 0.f; p2_ = 0.f; q11_ = 0.f; q22_ = 0.f; q12_ = 0.f;
    } else {
      LOADP(ub_, q12_, pr3)   // dual-critical fields first
      LOADP(vb1_, vb2_, pr0)
      LOADP(p1_, p2_, pr1)
      LOADP(q11_, q22_, pr2)
      u_ = *reinterpret_cast<const v2f*>(ug + base);  // primal-only
      LOADP(v1_, v2_, pr4)                            // primal-only
    }
  } else {
    f_ = 0.f; u_ = 0.f; ub_ = 0.f;
    v1_ = 0.f; v2_ = 0.f; vb1_ = 0.f; vb2_ = 0.f;
    p1_ = 0.f; p2_ = 0.f; q11_ = 0.f; q22_ = 0.f; q12_ = 0.f;
  }
#undef LOADP

  // Loop-invariant hoist (bit-exact: identical expression, computed once).
  const v2f fI = kTau * f_;

  if (interior) {
    run8<false>(ubS, vbS, p1S, p2S, q11S, q22S, q12S, rc, r, alpha0, alpha1,
                mD, mU, mR, mL, fI, u_, ub_, v1_, v2_, vb1_, vb2_, p1_, p2_,
                q11_, q22_, q12_);
  } else {
    run8<true>(ubS, vbS, p1S, p2S, q11S, q22S, q12S, rc, r, alpha0, alpha1,
               mD, mU, mR, mL, fI, u_, ub_, v1_, v2_, vb1_, vb2_, p1_, p2_,
               q11_, q22_, q12_);
  }

  // ---- store interior 16x32 (exact after 8 iters) ----
  if (r >= HALO && r < HALO + TILE_R && c >= HALO && c < HALO + TILE_C) {
#define STOREP(va, vb, dst)                              \
  {                                                      \
    float4 t4;                                           \
    t4.x = va.x; t4.y = vb.x; t4.z = va.y; t4.w = vb.y;  \
    *reinterpret_cast<float4*>((dst) + 2 * base) = t4;   \
  }
    *reinterpret_cast<v2f*>(ug + base) = u_;
    if (t0 != NLAUNCH - 1) {  // ws is dead after the final launch
      STOREP(vb1_, vb2_, pr0)
      STOREP(p1_, p2_, pr1)
      STOREP(q11_, q22_, pr2)
      STOREP(ub_, q12_, pr3)
      STOREP(v1_, v2_, pr4)
    }
#undef STOREP
  }
}

}  // namespace

extern "C" void kernel_launch(void* const* d_in, const int* in_sizes, int n_in,
                              void* d_out, int out_size, void* d_ws,
                              size_t ws_size, hipStream_t stream) {
  const float* f = (const float*)d_in[0];
  const float* rp = (const float*)d_in[1];  // [alpha0, alpha1]
  // d_in[2] is T = 128 (fixed; trip count must be static for graph capture).

  float* u = (float*)d_out;
  float* ws = (float*)d_ws;

  dim3 grid(256 / TILE_C, 256 / TILE_R, 2);  // 8 x 16 x 2 = 256 blocks
  for (int t = 0; t < NLAUNCH; ++t) {        // 16 launches x 8 iterations
    hipLaunchKernelGGL(tgv8_kernel, grid, dim3(NTHREADS), 0, stream, f, rp, u,
                       ws, t);
  }
}